// Round 18
// baseline (859.342 us; speedup 1.0000x reference)
//
#include <hip/hip_runtime.h>
#include <hip/hip_bf16.h>

// ---------------------------------------------------------------------------
// Model2: 5x 4-D conv (+ReLU) -> FC(3840->100)+ReLU -> FC(100->1)+sigmoid
// v18: v17 + (a) conv3 T=9 (12 loads -> 36 MFMAs: L1 1536 vs MFMA 2324
// cyc/CU -> MFMA-bound; viable now that XCD swizzle removed the HBM-latency
// exposure that sank v9's T=9), (b) conv1 T=5 (fp32 32B/lane loads made T=3
// L1-bound 2:1; T=5 -> 1.6:1).
// ---------------------------------------------------------------------------

#define BATCH 256
typedef unsigned int u32;
typedef float    f32x4  __attribute__((ext_vector_type(4)));
typedef float    f32x16 __attribute__((ext_vector_type(16)));
typedef _Float16 f16x8  __attribute__((ext_vector_type(8)));

struct __attribute__((packed, aligned(4))) f16x8w { f16x8 v; };  // 4B-aligned 16B load
struct __attribute__((packed, aligned(4))) f32x4u { f32x4 v; };  // 4B-aligned 16B load

// --------------------------- fused weight prepack --------------------------
__device__ __forceinline__ _Float16 conv_wf_elem(const float* __restrict__ w,
        int e, int COUT, int CIN, int KS, int S) {
    int j    = e & 7;
    int lane = (e >> 3) & 63;
    int st   = e >> 9;
    int k1 = st % KS;
    int r1 = st / KS;
    int k3p = r1 & 1;
    int r2  = r1 >> 1;
    int k2 = r2 % KS;
    int ci = r2 / KS;
    int gg = lane >> 5, col = lane & 31;
    int oc = col / S, s = col % S;
    int k3 = k3p * 2 + gg;
    int k4 = j - s;
    float v = 0.0f;
    if (oc < COUT && k3 < KS && k4 >= 0 && k4 < KS)
        v = w[((((oc * CIN + ci) * KS + k1) * KS + k2) * KS + k3) * KS + k4];
    return (_Float16)v;
}

__global__ void prepack_all(const float* __restrict__ w1, const float* __restrict__ w2,
                            const float* __restrict__ w3, const float* __restrict__ w4,
                            const float* __restrict__ w5, const float* __restrict__ fw,
                            _Float16* __restrict__ wf1, _Float16* __restrict__ wf2,
                            _Float16* __restrict__ wf3, _Float16* __restrict__ wf4,
                            _Float16* __restrict__ wf5, _Float16* __restrict__ wfc) {
    int idx = blockIdx.x * 256 + threadIdx.x;
    if (idx < 16384)  { wf1[idx] = conv_wf_elem(w1, idx, 3, 1, 4, 5);  return; }
    idx -= 16384;
    if (idx < 49152)  { wf2[idx] = conv_wf_elem(w2, idx, 9, 3, 4, 3);  return; }
    idx -= 49152;
    if (idx < 147456) { wf3[idx] = conv_wf_elem(w3, idx, 12, 9, 4, 2); return; }
    idx -= 147456;
    if (idx < 196608) { wf4[idx] = conv_wf_elem(w4, idx, 15, 12, 4, 2); return; }
    idx -= 196608;
    if (idx < 138240) { wf5[idx] = conv_wf_elem(w5, idx, 15, 15, 3, 2); return; }
    idx -= 138240;
    if (idx < 430080) {
        int j    = idx & 7;
        int lane = (idx >> 3) & 63;
        int t9   = idx >> 9;
        int st   = t9 % 120;
        int ni   = t9 / 120;
        int k    = st * 32 + (lane >> 4) * 8 + j;
        int col  = ni * 16 + (lane & 15);
        wfc[idx] = (_Float16)((col < 100) ? fw[k * 100 + col] : 0.0f);
    }
}

// --------------------------- LDS staging helper ----------------------------
template<int BYTES>
__device__ __forceinline__ void stage_b(const _Float16* gsrc, char* ldst, int tid) {
    constexpr int N16 = BYTES / 16;
    const int wv = tid >> 6, ln = tid & 63;
    #pragma unroll
    for (int it = 0; it * 256 < N16; ++it) {
        int u16 = it * 256 + (wv << 6);            // wave-uniform 16B-unit index
        if (u16 < N16) {
            const char* gp = (const char*)gsrc + (size_t)(u16 + ln) * 16;
            __builtin_amdgcn_global_load_lds(
                (const __attribute__((address_space(1))) unsigned int*)gp,
                (__attribute__((address_space(3))) unsigned int*)(ldst + u16 * 16),
                16, 0, 0);
        }
    }
}

// --------------------------- conv kernel (v18) -----------------------------
template<int CIN, int COUT, int KS, int DIN, int DP, int S, int OP, int T,
         int CG, int MINW, int FP32IN, int SODD, int WSHIFT, int XSWZ>
__launch_bounds__(256, MINW)
__global__ void conv4d_v18(const void* __restrict__ xin,
                           const void* __restrict__ xsin,
                           const _Float16* __restrict__ wf,
                           const float* __restrict__ bias,
                           _Float16* __restrict__ out,
                           _Float16* __restrict__ outs) {
    constexpr int ES = FP32IN ? 4 : 2;             // element bytes
    constexpr int DOUT = DIN - KS + 1;
    constexpr int NB   = (DOUT + S - 1) / S;
    constexpr int PCOL = DOUT * DOUT * NB;         // (d2,d3,u) rows per (b,d1)
    constexpr int NTC  = (PCOL + 31) / 32;
    constexpr int NG   = DOUT / T;                 // d1 groups
    static_assert(DOUT % T == 0, "T must divide DOUT");
    constexpr int XD2 = DIN * DP;
    constexpr int XD1 = DIN * XD2;
    constexpr int XCI = DIN * XD1;
    constexpr int GROUPS = CIN * KS * 2;
    static_assert(GROUPS % CG == 0, "CG must divide GROUPS");
    constexpr int CSTEPS = CG * KS;
    constexpr int CBYTES = CSTEPS * 1024;
    constexpr int NCHUNK = GROUPS / CG;
    constexpr int NBUF   = (NCHUNK > 1) ? 2 : 1;
    constexpr int AJ = T + KS - 1;                 // rows touched per group
    constexpr int W  = T + 1;                      // rolling window slots
    constexpr u32 NW   = (u32)BATCH * NG * NTC;
    constexpr u32 POUT = (u32)DOUT * DOUT * DOUT * OP;

    __shared__ char bsm[NBUF * CBYTES];
    const int tid = threadIdx.x;
    u32 bid = blockIdx.x;
    if (XSWZ) {
        u32 nwg = gridDim.x;            // divisible by 8 by construction
        u32 cpx = nwg >> 3;
        bid = (bid & 7u) * cpx + (bid >> 3);
    }
    u32 wid = bid * 4u + (u32)(tid >> 6);
    if (wid >= NW) wid = NW - 1u;
    const int ln = tid & 63;
    const int g  = ln >> 5;
    const int r  = ln & 31;

    u32 tc = wid % (u32)NTC;  u32 q = wid / (u32)NTC;
    u32 d1g = q % (u32)NG;    u32 b = q / (u32)NG;
    u32 rr = tc * 32u + (u32)r;  if (rr >= (u32)PCOL) rr = (u32)PCOL - 1u;
    u32 u  = rr % (u32)NB;    u32 q2 = rr / (u32)NB;
    u32 d3 = q2 % (u32)DOUT;  u32 d2 = q2 / (u32)DOUT;

    const u32 o = b * (u32)(CIN * XCI) + d1g * (u32)(T * XD1)
                + d2 * (u32)XD2 + d3 * (u32)DP + (u32)(g * DP) + u * (u32)S;
    const char* xb;
    if (FP32IN) {
        xb = (const char*)xin + (size_t)o * 4;
    } else if (SODD) {
        u32 p = o & 1u;
        xb = p ? ((const char*)xsin + (size_t)(o - 1u) * 2)
               : ((const char*)xin  + (size_t)o * 2);
    } else {
        xb = (const char*)xin + (size_t)o * 2;
    }

    auto load_frag = [&](const char* p) -> f16x8 {
        if constexpr (FP32IN) {
            f32x4 lo = ((const f32x4u*)p)->v;
            f32x4 hi = ((const f32x4u*)(p + 16))->v;
            f16x8 f;
            #pragma unroll
            for (int j = 0; j < 4; ++j) {
                f[j]     = (_Float16)lo[j];
                f[4 + j] = (_Float16)hi[j];
            }
            return f;
        } else {
            return ((const f16x8w*)p)->v;
        }
    };

    f32x16 acc[T];
    #pragma unroll
    for (int t = 0; t < T; ++t)
        #pragma unroll
        for (int i = 0; i < 16; ++i) acc[t][i] = 0.0f;

    stage_b<CBYTES>(wf, &bsm[0], tid);

    #pragma unroll 1
    for (int ch = 0; ch < NCHUNK; ++ch) {
        __syncthreads();   // staging for chunk ch complete (vmcnt drained)
        if (NCHUNK > 1 && ch + 1 < NCHUNK)
            stage_b<CBYTES>(wf + (size_t)(ch + 1) * CSTEPS * 512,
                            &bsm[((ch + 1) & 1) * CBYTES], tid);
        const char* bb = &bsm[(ch & 1) * (NBUF > 1 ? CBYTES : 0)] + ln * 16;
        #pragma unroll
        for (int gi = 0; gi < CG; ++gi) {
            int grp = ch * CG + gi;
            int k3p = grp & 1;
            int k2  = (grp >> 1) % KS;
            int ci  = (grp >> 1) / KS;
            u32 goff = ((u32)ci * (u32)XCI + (u32)k2 * (u32)XD2
                      + (u32)(k3p * 2 * DP)) * (u32)ES;
            const char* ap = xb + goff;

            // Rolling (T+1)-slot window; all indices compile-time constants.
            f16x8 ar[W];
            #pragma unroll
            for (int j = 0; j < T; ++j)
                ar[j] = load_frag(ap + j * (XD1 * ES));
            #pragma unroll
            for (int k1 = 0; k1 < KS; ++k1) {
                if (T + k1 < AJ)
                    ar[(T + k1) % W] = load_frag(ap + (T + k1) * (XD1 * ES));
                f16x8 bf = *(const f16x8*)(bb + (gi * KS + k1) * 1024);
                __builtin_amdgcn_s_setprio(1);
                #pragma unroll
                for (int t = 0; t < T; ++t)
                    acc[t] = __builtin_amdgcn_mfma_f32_32x32x16_f16(
                        ar[(k1 + t) % W], bf, acc[t], 0, 0, 0);
                __builtin_amdgcn_s_setprio(0);
            }
        }
    }

    // Epilogue. D: col = lane&31 = oc*S+s, row = (reg&3) + 8*(reg>>2) + 4*g.
    const int oc = r / S, s = r % S;
    if (oc >= COUT) return;
    float bv = bias[oc];
    #pragma unroll
    for (int reg = 0; reg < 16; ++reg) {
        int rowoff = (reg & 3) + 8 * (reg >> 2) + 4 * g;
        u32 rr2 = tc * 32u + (u32)rowoff;
        if (rr2 >= (u32)PCOL) rr2 = (u32)PCOL - 1u;
        u32 uu = rr2 % (u32)NB;  u32 qq = rr2 / (u32)NB;
        u32 dd3 = qq % (u32)DOUT; u32 dd2 = qq / (u32)DOUT;
        u32 d4 = uu * (u32)S + (u32)s;
        if (d4 < (u32)DOUT) {
            u32 obase = (b * (u32)COUT + (u32)oc) * POUT
                      + (dd2 * (u32)DOUT + dd3) * (u32)OP + d4
                      + d1g * (u32)(T * DOUT * DOUT * OP);
            #pragma unroll
            for (int t = 0; t < T; ++t) {
                u32 oidx = obase + (u32)t * (u32)(DOUT * DOUT * OP);
                _Float16 v = (_Float16)fmaxf(acc[t][reg] + bv, 0.0f);
                out[oidx] = v;
                if (WSHIFT) { if (oidx >= 1u) outs[oidx - 1u] = v; }
            }
        }
    }
}

// --------------------------- FC1 (MFMA 16x16x32) ---------------------------
__launch_bounds__(256)
__global__ void fc1_mfma(const _Float16* __restrict__ h,
                         const _Float16* __restrict__ wfc,
                         const float* __restrict__ bias,
                         float* __restrict__ o) {
    int wv   = blockIdx.x * 4 + (threadIdx.x >> 6);   // 0..111
    int lane = threadIdx.x & 63;
    int r = lane & 15, g = lane >> 4;
    int mi = wv / 7, ni = wv % 7;
    const f16x8* A  = (const f16x8*)(h + (size_t)(mi * 16 + r) * 3840);
    const f16x8* Bv = (const f16x8*)wfc;
    f32x4 acc = {0.f, 0.f, 0.f, 0.f};
    #pragma unroll 4
    for (int st = 0; st < 120; ++st) {
        f16x8 a = A[st * 4 + g];
        f16x8 b = Bv[(ni * 120 + st) * 64 + lane];
        acc = __builtin_amdgcn_mfma_f32_16x16x32_f16(a, b, acc, 0, 0, 0);
    }
    int col = ni * 16 + r;
    if (col < 100) {
        float bv = bias[col];
        #pragma unroll
        for (int i = 0; i < 4; ++i) {
            int row = mi * 16 + g * 4 + i;
            o[row * 100 + col] = fmaxf(acc[i] + bv, 0.0f);
        }
    }
}

// --------------------------- FC2 + sigmoid ---------------------------------
__global__ void fc2_sigmoid(const float* __restrict__ h,
                            const float* __restrict__ w,
                            const float* __restrict__ bias,
                            float* __restrict__ out) {
    int b = blockIdx.x * blockDim.x + threadIdx.x;
    if (b >= BATCH) return;
    const float* hb = h + b * 100;
    float acc = bias[0];
    #pragma unroll
    for (int j = 0; j < 100; ++j)
        acc = fmaf(hb[j], w[j], acc);
    out[b] = 1.0f / (1.0f + expf(-acc));
}

// --------------------------- launch ----------------------------------------
extern "C" void kernel_launch(void* const* d_in, const int* in_sizes, int n_in,
                              void* d_out, int out_size, void* d_ws, size_t ws_size,
                              hipStream_t stream) {
    const float* x    = (const float*)d_in[0];
    const float* w1   = (const float*)d_in[1];
    const float* b1   = (const float*)d_in[2];
    const float* w2   = (const float*)d_in[3];
    const float* b2   = (const float*)d_in[4];
    const float* w3   = (const float*)d_in[5];
    const float* b3   = (const float*)d_in[6];
    const float* w4   = (const float*)d_in[7];
    const float* b4   = (const float*)d_in[8];
    const float* w5   = (const float*)d_in[9];
    const float* b5   = (const float*)d_in[10];
    const float* fc1w = (const float*)d_in[11];
    const float* fc1b = (const float*)d_in[12];
    const float* fc2w = (const float*)d_in[13];
    const float* fc2b = (const float*)d_in[14];
    float* out = (float*)d_out;

    // Workspace (f16 units): [h1 41.47M][h1s 41.47M][h2 47.78M][wf tail].
    // h3/h4/h5 (28.35M) overlay h1 (dead after conv2).  Total ~264 MB.
    _Float16* W = (_Float16*)d_ws;
    _Float16* h1   = W;                       // 41,472,000
    _Float16* h1s  = W + 41472000;            // 41,472,000 (ends 82,944,000)
    _Float16* h2   = W + 82944000;            // 47,775,744 (ends 130,719,744)
    _Float16* h3   = h1;                      // 22,394,880 (overlay)
    _Float16* h4   = h1 + 22394880;           //  4,976,640
    _Float16* h5   = h1 + 27371520;           //    983,040
    _Float16* wf1  = W + 130719744;           //     16,384
    _Float16* wf2  = W + 130736128;           //     49,152
    _Float16* wf3  = W + 130785280;           //    147,456
    _Float16* wf4  = W + 130932736;           //    196,608
    _Float16* wf5  = W + 131129344;           //    138,240
    _Float16* wfc  = W + 131267584;           //    430,080
    float* fc1out  = (float*)(W + 131697664); //     25,600 f32

    prepack_all<<<3820, 256, 0, stream>>>(w1, w2, w3, w4, w5, fc1w,
                                          wf1, wf2, wf3, wf4, wf5, wfc);

    // convs: <CIN,COUT,KS,DIN,DP,S,OP,T,CG,MINW,FP32IN,SODD,WSHIFT,XSWZ>
    // conv1: fp32 direct, S=5, T=5 -> NG=3, NTC=22, NW=16896; grid 4224
    conv4d_v18<1, 3, 4, 18, 18, 5, 16, 5, 8, 3, 1, 0, 1, 1>
        <<<4224, 256, 0, stream>>>(x, x, wf1, b1, h1, h1s);
    // conv2: S=3, T=6 -> NG=2, NTC=18, NW=9216; grid 2304
    conv4d_v18<3, 9, 4, 15, 16, 3, 12, 6, 4, 3, 0, 1, 0, 1>
        <<<2304, 256, 0, stream>>>(h1, h1s, wf2, b2, h2, h2);
    // conv3: S=2, T=9 -> NG=1, NTC=13, NW=3328; grid 832 (104/XCD)
    conv4d_v18<9, 12, 4, 12, 12, 2, 10, 9, 4, 2, 0, 0, 0, 1>
        <<<832, 256, 0, stream>>>(h2, h2, wf3, b3, h3, h3);
    // conv4: T=2 -> NG=3, NTC=4, NW=3072; grid 768
    conv4d_v18<12, 15, 4, 9, 10, 2, 6, 2, 4, 4, 0, 0, 0, 1>
        <<<768, 256, 0, stream>>>(h3, h3, wf4, b4, h4, h4);
    // conv5: T=2 -> NG=2, NTC=1, NW=512; grid 128
    conv4d_v18<15, 15, 3, 6, 6, 2, 4, 2, 6, 4, 0, 0, 0, 0>
        <<<128, 256, 0, stream>>>(h4, h4, wf5, b5, h5, h5);

    fc1_mfma<<<28, 256, 0, stream>>>(h5, wfc, fc1b, fc1out);
    fc2_sigmoid<<<1, 256, 0, stream>>>(fc1out, fc2w, fc2b, out);
}

// Round 19
// 835.750 us; speedup vs baseline: 1.0282x; 1.0282x over previous
//
#include <hip/hip_runtime.h>
#include <hip/hip_bf16.h>

// ---------------------------------------------------------------------------
// Model2: 5x 4-D conv (+ReLU) -> FC(3840->100)+ReLU -> FC(100->1)+sigmoid
// v19: best-known per-layer configs. v18 with conv3 reverted to T=3 (v17's
// measured-best: T=9 regressed twice — 2 waves/SIMD + dispatch tail).
//   conv1 fp32-direct S=5 T=5 | conv2 S=3 T=6 | conv3 T=3 | conv4 T=2 |
//   conv5 T=2; XCD swizzle (T1) on conv1-4; setprio(1) around MFMA bursts.
// ---------------------------------------------------------------------------

#define BATCH 256
typedef unsigned int u32;
typedef float    f32x4  __attribute__((ext_vector_type(4)));
typedef float    f32x16 __attribute__((ext_vector_type(16)));
typedef _Float16 f16x8  __attribute__((ext_vector_type(8)));

struct __attribute__((packed, aligned(4))) f16x8w { f16x8 v; };  // 4B-aligned 16B load
struct __attribute__((packed, aligned(4))) f32x4u { f32x4 v; };  // 4B-aligned 16B load

// --------------------------- fused weight prepack --------------------------
__device__ __forceinline__ _Float16 conv_wf_elem(const float* __restrict__ w,
        int e, int COUT, int CIN, int KS, int S) {
    int j    = e & 7;
    int lane = (e >> 3) & 63;
    int st   = e >> 9;
    int k1 = st % KS;
    int r1 = st / KS;
    int k3p = r1 & 1;
    int r2  = r1 >> 1;
    int k2 = r2 % KS;
    int ci = r2 / KS;
    int gg = lane >> 5, col = lane & 31;
    int oc = col / S, s = col % S;
    int k3 = k3p * 2 + gg;
    int k4 = j - s;
    float v = 0.0f;
    if (oc < COUT && k3 < KS && k4 >= 0 && k4 < KS)
        v = w[((((oc * CIN + ci) * KS + k1) * KS + k2) * KS + k3) * KS + k4];
    return (_Float16)v;
}

__global__ void prepack_all(const float* __restrict__ w1, const float* __restrict__ w2,
                            const float* __restrict__ w3, const float* __restrict__ w4,
                            const float* __restrict__ w5, const float* __restrict__ fw,
                            _Float16* __restrict__ wf1, _Float16* __restrict__ wf2,
                            _Float16* __restrict__ wf3, _Float16* __restrict__ wf4,
                            _Float16* __restrict__ wf5, _Float16* __restrict__ wfc) {
    int idx = blockIdx.x * 256 + threadIdx.x;
    if (idx < 16384)  { wf1[idx] = conv_wf_elem(w1, idx, 3, 1, 4, 5);  return; }
    idx -= 16384;
    if (idx < 49152)  { wf2[idx] = conv_wf_elem(w2, idx, 9, 3, 4, 3);  return; }
    idx -= 49152;
    if (idx < 147456) { wf3[idx] = conv_wf_elem(w3, idx, 12, 9, 4, 2); return; }
    idx -= 147456;
    if (idx < 196608) { wf4[idx] = conv_wf_elem(w4, idx, 15, 12, 4, 2); return; }
    idx -= 196608;
    if (idx < 138240) { wf5[idx] = conv_wf_elem(w5, idx, 15, 15, 3, 2); return; }
    idx -= 138240;
    if (idx < 430080) {
        int j    = idx & 7;
        int lane = (idx >> 3) & 63;
        int t9   = idx >> 9;
        int st   = t9 % 120;
        int ni   = t9 / 120;
        int k    = st * 32 + (lane >> 4) * 8 + j;
        int col  = ni * 16 + (lane & 15);
        wfc[idx] = (_Float16)((col < 100) ? fw[k * 100 + col] : 0.0f);
    }
}

// --------------------------- LDS staging helper ----------------------------
template<int BYTES>
__device__ __forceinline__ void stage_b(const _Float16* gsrc, char* ldst, int tid) {
    constexpr int N16 = BYTES / 16;
    const int wv = tid >> 6, ln = tid & 63;
    #pragma unroll
    for (int it = 0; it * 256 < N16; ++it) {
        int u16 = it * 256 + (wv << 6);            // wave-uniform 16B-unit index
        if (u16 < N16) {
            const char* gp = (const char*)gsrc + (size_t)(u16 + ln) * 16;
            __builtin_amdgcn_global_load_lds(
                (const __attribute__((address_space(1))) unsigned int*)gp,
                (__attribute__((address_space(3))) unsigned int*)(ldst + u16 * 16),
                16, 0, 0);
        }
    }
}

// --------------------------- conv kernel (v19) -----------------------------
template<int CIN, int COUT, int KS, int DIN, int DP, int S, int OP, int T,
         int CG, int MINW, int FP32IN, int SODD, int WSHIFT, int XSWZ>
__launch_bounds__(256, MINW)
__global__ void conv4d_v19(const void* __restrict__ xin,
                           const void* __restrict__ xsin,
                           const _Float16* __restrict__ wf,
                           const float* __restrict__ bias,
                           _Float16* __restrict__ out,
                           _Float16* __restrict__ outs) {
    constexpr int ES = FP32IN ? 4 : 2;             // element bytes
    constexpr int DOUT = DIN - KS + 1;
    constexpr int NB   = (DOUT + S - 1) / S;
    constexpr int PCOL = DOUT * DOUT * NB;         // (d2,d3,u) rows per (b,d1)
    constexpr int NTC  = (PCOL + 31) / 32;
    constexpr int NG   = DOUT / T;                 // d1 groups
    static_assert(DOUT % T == 0, "T must divide DOUT");
    constexpr int XD2 = DIN * DP;
    constexpr int XD1 = DIN * XD2;
    constexpr int XCI = DIN * XD1;
    constexpr int GROUPS = CIN * KS * 2;
    static_assert(GROUPS % CG == 0, "CG must divide GROUPS");
    constexpr int CSTEPS = CG * KS;
    constexpr int CBYTES = CSTEPS * 1024;
    constexpr int NCHUNK = GROUPS / CG;
    constexpr int NBUF   = (NCHUNK > 1) ? 2 : 1;
    constexpr int AJ = T + KS - 1;                 // rows touched per group
    constexpr int W  = T + 1;                      // rolling window slots
    constexpr u32 NW   = (u32)BATCH * NG * NTC;
    constexpr u32 POUT = (u32)DOUT * DOUT * DOUT * OP;

    __shared__ char bsm[NBUF * CBYTES];
    const int tid = threadIdx.x;
    u32 bid = blockIdx.x;
    if (XSWZ) {
        u32 nwg = gridDim.x;            // divisible by 8 by construction
        u32 cpx = nwg >> 3;
        bid = (bid & 7u) * cpx + (bid >> 3);
    }
    u32 wid = bid * 4u + (u32)(tid >> 6);
    if (wid >= NW) wid = NW - 1u;
    const int ln = tid & 63;
    const int g  = ln >> 5;
    const int r  = ln & 31;

    u32 tc = wid % (u32)NTC;  u32 q = wid / (u32)NTC;
    u32 d1g = q % (u32)NG;    u32 b = q / (u32)NG;
    u32 rr = tc * 32u + (u32)r;  if (rr >= (u32)PCOL) rr = (u32)PCOL - 1u;
    u32 u  = rr % (u32)NB;    u32 q2 = rr / (u32)NB;
    u32 d3 = q2 % (u32)DOUT;  u32 d2 = q2 / (u32)DOUT;

    const u32 o = b * (u32)(CIN * XCI) + d1g * (u32)(T * XD1)
                + d2 * (u32)XD2 + d3 * (u32)DP + (u32)(g * DP) + u * (u32)S;
    const char* xb;
    if (FP32IN) {
        xb = (const char*)xin + (size_t)o * 4;
    } else if (SODD) {
        u32 p = o & 1u;
        xb = p ? ((const char*)xsin + (size_t)(o - 1u) * 2)
               : ((const char*)xin  + (size_t)o * 2);
    } else {
        xb = (const char*)xin + (size_t)o * 2;
    }

    auto load_frag = [&](const char* p) -> f16x8 {
        if constexpr (FP32IN) {
            f32x4 lo = ((const f32x4u*)p)->v;
            f32x4 hi = ((const f32x4u*)(p + 16))->v;
            f16x8 f;
            #pragma unroll
            for (int j = 0; j < 4; ++j) {
                f[j]     = (_Float16)lo[j];
                f[4 + j] = (_Float16)hi[j];
            }
            return f;
        } else {
            return ((const f16x8w*)p)->v;
        }
    };

    f32x16 acc[T];
    #pragma unroll
    for (int t = 0; t < T; ++t)
        #pragma unroll
        for (int i = 0; i < 16; ++i) acc[t][i] = 0.0f;

    stage_b<CBYTES>(wf, &bsm[0], tid);

    #pragma unroll 1
    for (int ch = 0; ch < NCHUNK; ++ch) {
        __syncthreads();   // staging for chunk ch complete (vmcnt drained)
        if (NCHUNK > 1 && ch + 1 < NCHUNK)
            stage_b<CBYTES>(wf + (size_t)(ch + 1) * CSTEPS * 512,
                            &bsm[((ch + 1) & 1) * CBYTES], tid);
        const char* bb = &bsm[(ch & 1) * (NBUF > 1 ? CBYTES : 0)] + ln * 16;
        #pragma unroll
        for (int gi = 0; gi < CG; ++gi) {
            int grp = ch * CG + gi;
            int k3p = grp & 1;
            int k2  = (grp >> 1) % KS;
            int ci  = (grp >> 1) / KS;
            u32 goff = ((u32)ci * (u32)XCI + (u32)k2 * (u32)XD2
                      + (u32)(k3p * 2 * DP)) * (u32)ES;
            const char* ap = xb + goff;

            // Rolling (T+1)-slot window; all indices compile-time constants.
            f16x8 ar[W];
            #pragma unroll
            for (int j = 0; j < T; ++j)
                ar[j] = load_frag(ap + j * (XD1 * ES));
            #pragma unroll
            for (int k1 = 0; k1 < KS; ++k1) {
                if (T + k1 < AJ)
                    ar[(T + k1) % W] = load_frag(ap + (T + k1) * (XD1 * ES));
                f16x8 bf = *(const f16x8*)(bb + (gi * KS + k1) * 1024);
                __builtin_amdgcn_s_setprio(1);
                #pragma unroll
                for (int t = 0; t < T; ++t)
                    acc[t] = __builtin_amdgcn_mfma_f32_32x32x16_f16(
                        ar[(k1 + t) % W], bf, acc[t], 0, 0, 0);
                __builtin_amdgcn_s_setprio(0);
            }
        }
    }

    // Epilogue. D: col = lane&31 = oc*S+s, row = (reg&3) + 8*(reg>>2) + 4*g.
    const int oc = r / S, s = r % S;
    if (oc >= COUT) return;
    float bv = bias[oc];
    #pragma unroll
    for (int reg = 0; reg < 16; ++reg) {
        int rowoff = (reg & 3) + 8 * (reg >> 2) + 4 * g;
        u32 rr2 = tc * 32u + (u32)rowoff;
        if (rr2 >= (u32)PCOL) rr2 = (u32)PCOL - 1u;
        u32 uu = rr2 % (u32)NB;  u32 qq = rr2 / (u32)NB;
        u32 dd3 = qq % (u32)DOUT; u32 dd2 = qq / (u32)DOUT;
        u32 d4 = uu * (u32)S + (u32)s;
        if (d4 < (u32)DOUT) {
            u32 obase = (b * (u32)COUT + (u32)oc) * POUT
                      + (dd2 * (u32)DOUT + dd3) * (u32)OP + d4
                      + d1g * (u32)(T * DOUT * DOUT * OP);
            #pragma unroll
            for (int t = 0; t < T; ++t) {
                u32 oidx = obase + (u32)t * (u32)(DOUT * DOUT * OP);
                _Float16 v = (_Float16)fmaxf(acc[t][reg] + bv, 0.0f);
                out[oidx] = v;
                if (WSHIFT) { if (oidx >= 1u) outs[oidx - 1u] = v; }
            }
        }
    }
}

// --------------------------- FC1 (MFMA 16x16x32) ---------------------------
__launch_bounds__(256)
__global__ void fc1_mfma(const _Float16* __restrict__ h,
                         const _Float16* __restrict__ wfc,
                         const float* __restrict__ bias,
                         float* __restrict__ o) {
    int wv   = blockIdx.x * 4 + (threadIdx.x >> 6);   // 0..111
    int lane = threadIdx.x & 63;
    int r = lane & 15, g = lane >> 4;
    int mi = wv / 7, ni = wv % 7;
    const f16x8* A  = (const f16x8*)(h + (size_t)(mi * 16 + r) * 3840);
    const f16x8* Bv = (const f16x8*)wfc;
    f32x4 acc = {0.f, 0.f, 0.f, 0.f};
    #pragma unroll 4
    for (int st = 0; st < 120; ++st) {
        f16x8 a = A[st * 4 + g];
        f16x8 b = Bv[(ni * 120 + st) * 64 + lane];
        acc = __builtin_amdgcn_mfma_f32_16x16x32_f16(a, b, acc, 0, 0, 0);
    }
    int col = ni * 16 + r;
    if (col < 100) {
        float bv = bias[col];
        #pragma unroll
        for (int i = 0; i < 4; ++i) {
            int row = mi * 16 + g * 4 + i;
            o[row * 100 + col] = fmaxf(acc[i] + bv, 0.0f);
        }
    }
}

// --------------------------- FC2 + sigmoid ---------------------------------
__global__ void fc2_sigmoid(const float* __restrict__ h,
                            const float* __restrict__ w,
                            const float* __restrict__ bias,
                            float* __restrict__ out) {
    int b = blockIdx.x * blockDim.x + threadIdx.x;
    if (b >= BATCH) return;
    const float* hb = h + b * 100;
    float acc = bias[0];
    #pragma unroll
    for (int j = 0; j < 100; ++j)
        acc = fmaf(hb[j], w[j], acc);
    out[b] = 1.0f / (1.0f + expf(-acc));
}

// --------------------------- launch ----------------------------------------
extern "C" void kernel_launch(void* const* d_in, const int* in_sizes, int n_in,
                              void* d_out, int out_size, void* d_ws, size_t ws_size,
                              hipStream_t stream) {
    const float* x    = (const float*)d_in[0];
    const float* w1   = (const float*)d_in[1];
    const float* b1   = (const float*)d_in[2];
    const float* w2   = (const float*)d_in[3];
    const float* b2   = (const float*)d_in[4];
    const float* w3   = (const float*)d_in[5];
    const float* b3   = (const float*)d_in[6];
    const float* w4   = (const float*)d_in[7];
    const float* b4   = (const float*)d_in[8];
    const float* w5   = (const float*)d_in[9];
    const float* b5   = (const float*)d_in[10];
    const float* fc1w = (const float*)d_in[11];
    const float* fc1b = (const float*)d_in[12];
    const float* fc2w = (const float*)d_in[13];
    const float* fc2b = (const float*)d_in[14];
    float* out = (float*)d_out;

    // Workspace (f16 units): [h1 41.47M][h1s 41.47M][h2 47.78M][wf tail].
    // h3/h4/h5 (28.35M) overlay h1 (dead after conv2).  Total ~264 MB.
    _Float16* W = (_Float16*)d_ws;
    _Float16* h1   = W;                       // 41,472,000
    _Float16* h1s  = W + 41472000;            // 41,472,000 (ends 82,944,000)
    _Float16* h2   = W + 82944000;            // 47,775,744 (ends 130,719,744)
    _Float16* h3   = h1;                      // 22,394,880 (overlay)
    _Float16* h4   = h1 + 22394880;           //  4,976,640
    _Float16* h5   = h1 + 27371520;           //    983,040
    _Float16* wf1  = W + 130719744;           //     16,384
    _Float16* wf2  = W + 130736128;           //     49,152
    _Float16* wf3  = W + 130785280;           //    147,456
    _Float16* wf4  = W + 130932736;           //    196,608
    _Float16* wf5  = W + 131129344;           //    138,240
    _Float16* wfc  = W + 131267584;           //    430,080
    float* fc1out  = (float*)(W + 131697664); //     25,600 f32

    prepack_all<<<3820, 256, 0, stream>>>(w1, w2, w3, w4, w5, fc1w,
                                          wf1, wf2, wf3, wf4, wf5, wfc);

    // convs: <CIN,COUT,KS,DIN,DP,S,OP,T,CG,MINW,FP32IN,SODD,WSHIFT,XSWZ>
    // conv1: fp32 direct, S=5, T=5 -> NG=3, NTC=22, NW=16896; grid 4224
    conv4d_v19<1, 3, 4, 18, 18, 5, 16, 5, 8, 3, 1, 0, 1, 1>
        <<<4224, 256, 0, stream>>>(x, x, wf1, b1, h1, h1s);
    // conv2: S=3, T=6 -> NG=2, NTC=18, NW=9216; grid 2304
    conv4d_v19<3, 9, 4, 15, 16, 3, 12, 6, 4, 3, 0, 1, 0, 1>
        <<<2304, 256, 0, stream>>>(h1, h1s, wf2, b2, h2, h2);
    // conv3: T=3 (v17 measured-best) -> NG=3, NTC=13, NW=9984; grid 2496
    conv4d_v19<9, 12, 4, 12, 12, 2, 10, 3, 4, 4, 0, 0, 0, 1>
        <<<2496, 256, 0, stream>>>(h2, h2, wf3, b3, h3, h3);
    // conv4: T=2 -> NG=3, NTC=4, NW=3072; grid 768
    conv4d_v19<12, 15, 4, 9, 10, 2, 6, 2, 4, 4, 0, 0, 0, 1>
        <<<768, 256, 0, stream>>>(h3, h3, wf4, b4, h4, h4);
    // conv5: T=2 -> NG=2, NTC=1, NW=512; grid 128
    conv4d_v19<15, 15, 3, 6, 6, 2, 4, 2, 6, 4, 0, 0, 0, 0>
        <<<128, 256, 0, stream>>>(h4, h4, wf5, b5, h5, h5);

    fc1_mfma<<<28, 256, 0, stream>>>(h5, wfc, fc1b, fc1out);
    fc2_sigmoid<<<1, 256, 0, stream>>>(fc1out, fc2w, fc2b, out);
}